// Round 7
// baseline (659.152 us; speedup 1.0000x reference)
//
#include <hip/hip_runtime.h>
#include <cstdint>

#define TT 8000
#define NB 4

typedef _Float16 half8 __attribute__((ext_vector_type(8)));
typedef float f32x4 __attribute__((ext_vector_type(4)));

static __device__ __forceinline__ f32x4 MFMA16(half8 a, half8 b, f32x4 c){
  return __builtin_amdgcn_mfma_f32_16x16x32_f16(a, b, c, 0, 0, 0);
}

static __device__ __forceinline__ float gatef(float a, float b){
  a = fminf(fmaxf(a, -20.f), 20.f);
  float e2a = __expf(2.f*a);
  float th = __fdividef(e2a - 1.f, e2a + 1.f);
  float sg = __fdividef(1.f, 1.f + __expf(-b));
  return th * sg;
}

union PK4 { uint64_t u; _Float16 h[4]; };

// ---------------- prep: convert/pack all weights to f16 MFMA-A layouts ----------------
__global__ void prep_kernel(const float* __restrict__ dil_w, const float* __restrict__ cond_w,
                            const float* __restrict__ res_w, const float* __restrict__ skip_w,
                            const float* __restrict__ cow, const float* __restrict__ cew,
                            const float* __restrict__ skip_b,
                            _Float16* __restrict__ WdT, _Float16* __restrict__ Wc,
                            _Float16* __restrict__ Wr, _Float16* __restrict__ Wsa,
                            _Float16* __restrict__ Wco, _Float16* __restrict__ Wce,
                            float* __restrict__ bsum)
{
  int g = blockIdx.x*256 + threadIdx.x;
  if (g < 262144){
    int r = g & 63, m = (g>>6) & 127, tap = (g>>13) & 1, l = g>>14;
    WdT[g] = (_Float16)dil_w[(((l*128+m)*64 + r)*2) + tap];
  } else if ((g -= 262144) < 196608){
    int o = g % 96; int rest = g / 96; int m = rest & 127; int l = rest >> 7;
    Wc[g] = (_Float16)((o < 80) ? cond_w[(l*128+m)*80 + o] : 0.f);
  } else if ((g -= 196608) < 61440){
    Wr[g] = (_Float16)res_w[g];
  } else if ((g -= 61440) < 262144){
    int kk = g & 1023, m = g >> 10; int l = kk >> 6, j = kk & 63;
    Wsa[g] = (_Float16)skip_w[(l*256+m)*64 + j];
  } else if ((g -= 262144) < 65536){
    Wco[g] = (_Float16)cow[g];
  } else if ((g -= 65536) < 65536){
    Wce[g] = (_Float16)cew[g];
  } else if ((g -= 65536) < 256){
    float s = 0.f;
    for (int l = 0; l < 16; l++) s += skip_b[l*256 + g];
    bsum[g] = s;
  }
}

// ---------------- upsample: block (tc,o) covers 1024 t; weight slice reused 4x --------
// cond[n][o][t] = up_b[o] + sum_{i,ds} feat[n][i][s] * up_w[o][i][256ds+tid], s=4tc+q-ds
__global__ __launch_bounds__(256) void upsample_kernel(
    const float* __restrict__ feat, const float* __restrict__ up_w,
    const float* __restrict__ up_b, float* __restrict__ condf)
{
  int tc = blockIdx.x, o = blockIdx.y, tid = threadIdx.x;
  float ub = up_b[o];
  float acc[4][4]; // [q][n]
  #pragma unroll
  for (int q = 0; q < 4; q++)
    #pragma unroll
    for (int n = 0; n < 4; n++) acc[q][n] = ub;

  #pragma unroll
  for (int ds = 0; ds < 4; ds++){
    const float* wb = up_w + (size_t)o*81920 + 256*ds + tid;
    for (int i = 0; i < 80; i++){
      float wv = wb[(size_t)i*1024];
      #pragma unroll
      for (int q = 0; q < 4; q++){
        int s = 4*tc + q - ds;
        if (s >= 0){
          const float* fb = feat + (size_t)i*32 + s;
          #pragma unroll
          for (int n = 0; n < 4; n++)
            acc[q][n] = __fmaf_rn(wv, fb[(size_t)n*2560], acc[q][n]);
        }
      }
    }
  }
  #pragma unroll
  for (int q = 0; q < 4; q++){
    int t = tc*1024 + q*256 + tid;
    if (t < TT){
      #pragma unroll
      for (int n = 0; n < 4; n++)
        condf[((size_t)(n*80+o))*TT + t] = acc[q][n];
    }
  }
}

// ---------------- condpack: cond fp32 [n][80][T] -> f16 [n][T][96] (pad 0) ------------
__global__ __launch_bounds__(256) void condpack_kernel(
    const float* __restrict__ condf, _Float16* __restrict__ condh)
{
  __shared__ float ls[64*101];
  int t0 = blockIdx.x*64, n = blockIdx.y, tid = threadIdx.x;
  for (int e = tid; e < 5120; e += 256){
    int ch = e >> 6, tl = e & 63;
    ls[tl*101 + ch] = condf[((size_t)(n*80+ch))*TT + t0 + tl];
  }
  __syncthreads();
  uint32_t* dst = (uint32_t*)condh;
  for (int e = tid; e < 3072; e += 256){
    int tl = e / 48, cp = e % 48; int c0 = cp*2;
    float f0 = (c0   < 80) ? ls[tl*101 + c0]   : 0.f;
    float f1 = (c0+1 < 80) ? ls[tl*101 + c0+1] : 0.f;
    _Float16 h0 = (_Float16)f0, h1 = (_Float16)f1;
    uint16_t u0 = *(uint16_t*)&h0, u1 = *(uint16_t*)&h1;
    dst[((size_t)n*TT + t0 + tl)*48 + cp] = ((uint32_t)u1 << 16) | u0;
  }
}

// ---------------- embedding -> xf [n][t][64] f32 + xh [n][t][64] f16 ------------------
__global__ __launch_bounds__(256) void embed_kernel(
    const int* __restrict__ fi, const float* __restrict__ embed,
    float* __restrict__ xf, _Float16* __restrict__ xh)
{
  int tile = blockIdx.x, n = blockIdx.y;
  int tl = threadIdx.x >> 2, g = threadIdx.x & 3;
  int t = tile*64 + tl;
  int idx = fi[(size_t)n*TT + t];
  const float* er = embed + (size_t)idx*64 + g*16;
  float* xo = xf + ((size_t)n*TT + t)*64 + g*16;
  _Float16* ho = xh + ((size_t)n*TT + t)*64 + g*16;
  #pragma unroll
  for (int r = 0; r < 16; r++){
    float v = er[r];
    xo[r] = v;
    ho[r] = (_Float16)v;
  }
}

// ---------------- one residual layer, f16 MFMA, t-major activations -------------------
// block 256 = 4 waves; wave w owns in_act M-tiles {w, w+4} (tanh/sigmoid in same wave).
template<bool LAST>
__global__ __launch_bounds__(256) void layer_mfma(
    float* __restrict__ xf,               // [n][t][64] f32, in-place residual
    const _Float16* __restrict__ xh_in,   // [n][t][64] f16
    _Float16* __restrict__ xh_out,        // [n][t][64] f16
    const _Float16* __restrict__ condh,   // [n][t][96]
    _Float16* __restrict__ actsL,         // actsG + l*64, [n][t][1024]
    const _Float16* __restrict__ WdT,     // [2][128][64]
    const _Float16* __restrict__ Wc,      // [128][96]
    const _Float16* __restrict__ Wr,      // [64][64]
    const float* __restrict__ dil_b_l,
    const float* __restrict__ cond_b_l,
    const float* __restrict__ res_b_l,
    int d)
{
  __shared__ __attribute__((aligned(16))) char als[8192];  // [64 t][64 ch] f16, swizzled
  int bx = blockIdx.x;
  int tile = bx % 125, n = bx / 125;
  int tid = threadIdx.x;
  int lane = tid & 63;
  int w = tid >> 6;
  int t0 = tile*64;
  int l16 = lane & 15;
  int lg  = lane >> 4;
  const _Float16* xhn = xh_in + (size_t)n*TT*64;

  // ---- A fragments (L2-resident weights) ----
  half8 aD[2][2][2];   // [tap][mi][ks]
  half8 aC[2][3];      // [mi][kc]
  #pragma unroll
  for (int mi = 0; mi < 2; mi++){
    int m = (w + 4*mi)*16 + l16;
    #pragma unroll
    for (int tap = 0; tap < 2; tap++)
      #pragma unroll
      for (int ks = 0; ks < 2; ks++)
        aD[tap][mi][ks] = *(const half8*)(WdT + ((size_t)(tap*128 + m)*64 + ks*32 + lg*8));
    #pragma unroll
    for (int kc = 0; kc < 3; kc++)
      aC[mi][kc] = *(const half8*)(Wc + ((size_t)m*96 + kc*32 + lg*8));
  }
  float bias[2][4];
  #pragma unroll
  for (int mi = 0; mi < 2; mi++)
    #pragma unroll
    for (int r = 0; r < 4; r++){
      int mm = (w + 4*mi)*16 + lg*4 + r;
      bias[mi][r] = dil_b_l[mm] + cond_b_l[mm];
    }

  f32x4 acc[2][4];
  #pragma unroll
  for (int nt = 0; nt < 4; nt++){
    int t = t0 + nt*16 + l16;
    int td = t - d;
    half8 bcur[2], bdel[2], bcnd[3];
    #pragma unroll
    for (int ks = 0; ks < 2; ks++)
      bcur[ks] = *(const half8*)(xhn + (size_t)t*64 + ks*32 + lg*8);
    if (td >= 0){
      #pragma unroll
      for (int ks = 0; ks < 2; ks++)
        bdel[ks] = *(const half8*)(xhn + (size_t)td*64 + ks*32 + lg*8);
    } else {
      #pragma unroll
      for (int ks = 0; ks < 2; ks++)
        #pragma unroll
        for (int j = 0; j < 8; j++) bdel[ks][j] = (_Float16)0.f;
    }
    #pragma unroll
    for (int kc = 0; kc < 3; kc++)
      bcnd[kc] = *(const half8*)(condh + ((size_t)n*TT + t)*96 + kc*32 + lg*8);

    #pragma unroll
    for (int mi = 0; mi < 2; mi++){
      f32x4 a; a[0]=bias[mi][0]; a[1]=bias[mi][1]; a[2]=bias[mi][2]; a[3]=bias[mi][3];
      a = MFMA16(aD[0][mi][0], bdel[0], a);
      a = MFMA16(aD[0][mi][1], bdel[1], a);
      a = MFMA16(aD[1][mi][0], bcur[0], a);
      a = MFMA16(aD[1][mi][1], bcur[1], a);
      a = MFMA16(aC[mi][0], bcnd[0], a);
      a = MFMA16(aC[mi][1], bcnd[1], a);
      a = MFMA16(aC[mi][2], bcnd[2], a);
      acc[mi][nt] = a;
    }
  }

  // ---- gate + acts (f16) -> LDS (swizzled) + global ----
  int ch0 = w*16 + lg*4;
  #pragma unroll
  for (int nt = 0; nt < 4; nt++){
    int tl = nt*16 + l16;
    PK4 pk;
    #pragma unroll
    for (int r = 0; r < 4; r++)
      pk.h[r] = (_Float16)gatef(acc[0][nt][r], acc[1][nt][r]);
    if (!LAST)
      *(uint64_t*)(als + tl*128 + ((ch0*2) ^ ((tl & 7) << 4))) = pk.u;
    *(uint64_t*)(actsL + ((size_t)n*TT + t0 + tl)*1024 + ch0) = pk.u;
  }

  if (!LAST){
    __syncthreads();
    // ---- res GEMM: x += Wr @ acts + res_b ; also write xh_out f16 ----
    half8 aR[2];
    int mr = w*16 + l16;
    #pragma unroll
    for (int ks = 0; ks < 2; ks++)
      aR[ks] = *(const half8*)(Wr + (size_t)mr*64 + ks*32 + lg*8);
    float rb[4];
    #pragma unroll
    for (int r = 0; r < 4; r++) rb[r] = res_b_l[w*16 + lg*4 + r];
    #pragma unroll
    for (int nt = 0; nt < 4; nt++){
      int tl = nt*16 + l16; int t = t0 + tl;
      half8 bA[2];
      #pragma unroll
      for (int ks = 0; ks < 2; ks++)
        bA[ks] = *(const half8*)(als + tl*128 + (((ks*32 + lg*8)*2) ^ ((tl & 7) << 4)));
      f32x4 rc; rc[0]=rb[0]; rc[1]=rb[1]; rc[2]=rb[2]; rc[3]=rb[3];
      rc = MFMA16(aR[0], bA[0], rc);
      rc = MFMA16(aR[1], bA[1], rc);
      float* xp = xf + ((size_t)n*TT + t)*64 + w*16 + lg*4;
      f32x4 xv = *(const f32x4*)xp;
      xv += rc;
      *(f32x4*)xp = xv;
      PK4 pk;
      #pragma unroll
      for (int r = 0; r < 4; r++) pk.h[r] = (_Float16)xv[r];
      *(uint64_t*)(xh_out + ((size_t)n*TT + t)*64 + w*16 + lg*4) = pk.u;
    }
  }
}

// ---------------- fused final: skip-sum(K=1024)->relu->conv_out->relu->conv_end->shift
// 512 threads = 8 waves; wave w owns M-tiles {2w, 2w+1}
__global__ __launch_bounds__(512) void final_fused(
    const _Float16* __restrict__ actsG,  // [n][t][1024]
    const _Float16* __restrict__ Wsa,    // [256][1024]
    const _Float16* __restrict__ Wco,    // [256][256]
    const _Float16* __restrict__ Wce,    // [256][256]
    const float* __restrict__ bsum,      // [256]
    float* __restrict__ out)             // [n][256][8000]
{
  __shared__ __attribute__((aligned(16))) char ls[32768]; // [64 t][256 ch] f16, swizzled
  int bx = blockIdx.x;
  int tile = bx % 125, n = bx / 125;
  int tid = threadIdx.x;
  int lane = tid & 63;
  int w = tid >> 6;         // 0..7
  int t0 = tile*64;
  int l16 = lane & 15;
  int lg  = lane >> 4;

  // phase 1: skip-sum GEMM (K=1024)
  f32x4 acc[2][4];
  #pragma unroll
  for (int mi = 0; mi < 2; mi++)
    #pragma unroll
    for (int nt = 0; nt < 4; nt++){
      f32x4 a;
      #pragma unroll
      for (int r = 0; r < 4; r++) a[r] = bsum[(2*w+mi)*16 + lg*4 + r];
      acc[mi][nt] = a;
    }
  for (int ks = 0; ks < 32; ks++){
    half8 bf[4];
    #pragma unroll
    for (int nt = 0; nt < 4; nt++){
      int t = t0 + nt*16 + l16;
      bf[nt] = *(const half8*)(actsG + ((size_t)n*TT + t)*1024 + ks*32 + lg*8);
    }
    #pragma unroll
    for (int mi = 0; mi < 2; mi++){
      int m = (2*w+mi)*16 + l16;
      half8 af = *(const half8*)(Wsa + (size_t)m*1024 + ks*32 + lg*8);
      #pragma unroll
      for (int nt = 0; nt < 4; nt++) acc[mi][nt] = MFMA16(af, bf[nt], acc[mi][nt]);
    }
  }
  #pragma unroll
  for (int mi = 0; mi < 2; mi++){
    int c0 = (2*w+mi)*16 + lg*4;
    #pragma unroll
    for (int nt = 0; nt < 4; nt++){
      int tl = nt*16 + l16;
      PK4 pk;
      #pragma unroll
      for (int r = 0; r < 4; r++) pk.h[r] = (_Float16)fmaxf(acc[mi][nt][r], 0.f);
      *(uint64_t*)(ls + tl*512 + ((c0*2) ^ ((tl & 15) << 4))) = pk.u;
    }
  }
  __syncthreads();

  // phase 2: conv_out (K=256)
  #pragma unroll
  for (int mi = 0; mi < 2; mi++)
    #pragma unroll
    for (int nt = 0; nt < 4; nt++){ f32x4 a; a[0]=0;a[1]=0;a[2]=0;a[3]=0; acc[mi][nt]=a; }
  #pragma unroll
  for (int ks = 0; ks < 8; ks++){
    half8 bf[4];
    #pragma unroll
    for (int nt = 0; nt < 4; nt++){
      int tl = nt*16 + l16;
      bf[nt] = *(const half8*)(ls + tl*512 + (((ks*32 + lg*8)*2) ^ ((tl & 15) << 4)));
    }
    #pragma unroll
    for (int mi = 0; mi < 2; mi++){
      int m = (2*w+mi)*16 + l16;
      half8 af = *(const half8*)(Wco + (size_t)m*256 + ks*32 + lg*8);
      #pragma unroll
      for (int nt = 0; nt < 4; nt++) acc[mi][nt] = MFMA16(af, bf[nt], acc[mi][nt]);
    }
  }
  __syncthreads();
  #pragma unroll
  for (int mi = 0; mi < 2; mi++){
    int c0 = (2*w+mi)*16 + lg*4;
    #pragma unroll
    for (int nt = 0; nt < 4; nt++){
      int tl = nt*16 + l16;
      PK4 pk;
      #pragma unroll
      for (int r = 0; r < 4; r++) pk.h[r] = (_Float16)fmaxf(acc[mi][nt][r], 0.f);
      *(uint64_t*)(ls + tl*512 + ((c0*2) ^ ((tl & 15) << 4))) = pk.u;
    }
  }
  __syncthreads();

  // phase 3: conv_end (K=256) + shifted store
  #pragma unroll
  for (int mi = 0; mi < 2; mi++)
    #pragma unroll
    for (int nt = 0; nt < 4; nt++){ f32x4 a; a[0]=0;a[1]=0;a[2]=0;a[3]=0; acc[mi][nt]=a; }
  #pragma unroll
  for (int ks = 0; ks < 8; ks++){
    half8 bf[4];
    #pragma unroll
    for (int nt = 0; nt < 4; nt++){
      int tl = nt*16 + l16;
      bf[nt] = *(const half8*)(ls + tl*512 + (((ks*32 + lg*8)*2) ^ ((tl & 15) << 4)));
    }
    #pragma unroll
    for (int mi = 0; mi < 2; mi++){
      int m = (2*w+mi)*16 + l16;
      half8 af = *(const half8*)(Wce + (size_t)m*256 + ks*32 + lg*8);
      #pragma unroll
      for (int nt = 0; nt < 4; nt++) acc[mi][nt] = MFMA16(af, bf[nt], acc[mi][nt]);
    }
  }
  #pragma unroll
  for (int mi = 0; mi < 2; mi++)
    #pragma unroll
    for (int nt = 0; nt < 4; nt++)
      #pragma unroll
      for (int r = 0; r < 4; r++){
        int m = (2*w+mi)*16 + lg*4 + r;
        int t = t0 + nt*16 + l16;
        size_t ob = ((size_t)n*256 + m)*TT;
        if (t + 1 < TT) out[ob + t + 1] = acc[mi][nt][r];
        if (t == 0)     out[ob] = 0.f;
      }
}

extern "C" void kernel_launch(void* const* d_in, const int* in_sizes, int n_in,
                              void* d_out, int out_size, void* d_ws, size_t ws_size,
                              hipStream_t stream)
{
  const float* feat   = (const float*)d_in[0];
  const int*   fi     = (const int*)  d_in[1];
  const float* embed  = (const float*)d_in[2];
  const float* up_w   = (const float*)d_in[3];
  const float* up_b   = (const float*)d_in[4];
  const float* cond_w = (const float*)d_in[5];
  const float* cond_b = (const float*)d_in[6];
  const float* dil_w  = (const float*)d_in[7];
  const float* dil_b  = (const float*)d_in[8];
  const float* res_w  = (const float*)d_in[9];
  const float* res_b  = (const float*)d_in[10];
  const float* skip_w = (const float*)d_in[11];
  const float* skip_b = (const float*)d_in[12];
  const float* cow    = (const float*)d_in[13];
  const float* cew    = (const float*)d_in[14];
  float* out = (float*)d_out;
  float* cur = (float*)d_ws;

  float*     xf    = cur;               cur += 2048000;   // [4][8000][64] f32 = 2,048,000 floats
  _Float16*  xhA   = (_Float16*)cur;    cur += 1024000;   // 2,048,000 f16 = 1,024,000 floats
  _Float16*  xhB   = (_Float16*)cur;    cur += 1024000;
  _Float16*  condh = (_Float16*)cur;    cur += 1536000;   // [4][8000][96] f16 = 3,072,000 f16 = 1,536,000 floats (was 768000: overran into weights!)
  _Float16*  WdT   = (_Float16*)cur;    cur += 131072;    // 262,144 f16
  _Float16*  Wc    = (_Float16*)cur;    cur += 98304;     // 196,608 f16
  _Float16*  Wr    = (_Float16*)cur;    cur += 30720;     // 61,440 f16
  _Float16*  Wsa   = (_Float16*)cur;    cur += 131072;    // 262,144 f16
  _Float16*  Wco   = (_Float16*)cur;    cur += 32768;
  _Float16*  Wce   = (_Float16*)cur;    cur += 32768;
  float*     bsum  = cur;               cur += 256;
  _Float16*  actsG = (_Float16*)cur;                      // [4][8000][1024] f16 (65.5 MB)
  float*     condf = cur;               // overlay: fp32 cond dead before actsG written

  prep_kernel<<<3569, 256, 0, stream>>>(dil_w, cond_w, res_w, skip_w, cow, cew, skip_b,
                                        WdT, Wc, Wr, Wsa, Wco, Wce, bsum);
  upsample_kernel<<<dim3(8,80), 256, 0, stream>>>(feat, up_w, up_b, condf);
  condpack_kernel<<<dim3(125,4), 256, 0, stream>>>(condf, condh);
  embed_kernel<<<dim3(125,4), 256, 0, stream>>>(fi, embed, xf, xhA);

  const _Float16* xhin = xhA; _Float16* xhout = xhB;
  for (int l = 0; l < 16; l++){
    int dd = 1 << (l & 7);
    const _Float16* WdTl = WdT + (size_t)l*16384;
    const _Float16* Wcl  = Wc  + (size_t)l*12288;
    const _Float16* Wrl  = Wr  + (size_t)(l < 15 ? l : 0)*4096;
    const float*    rbl  = res_b + (size_t)(l < 15 ? l : 0)*64;
    _Float16* actsL = actsG + (size_t)l*64;
    if (l == 15)
      layer_mfma<true><<<500, 256, 0, stream>>>(xf, xhin, xhout, condh, actsL,
          WdTl, Wcl, Wrl, dil_b + l*128, cond_b + l*128, rbl, dd);
    else
      layer_mfma<false><<<500, 256, 0, stream>>>(xf, xhin, xhout, condh, actsL,
          WdTl, Wcl, Wrl, dil_b + l*128, cond_b + l*128, rbl, dd);
    const _Float16* nin = xhout; xhout = (_Float16*)xhin; xhin = nin;
  }

  final_fused<<<500, 512, 0, stream>>>(actsG, Wsa, Wco, Wce, bsum, out);
}

// Round 8
// 503.319 us; speedup vs baseline: 1.3096x; 1.3096x over previous
//
#include <hip/hip_runtime.h>
#include <cstdint>

#define TT 8000
#define NB 4

typedef _Float16 half8 __attribute__((ext_vector_type(8)));
typedef float f32x4 __attribute__((ext_vector_type(4)));

static __device__ __forceinline__ f32x4 MFMA16(half8 a, half8 b, f32x4 c){
  return __builtin_amdgcn_mfma_f32_16x16x32_f16(a, b, c, 0, 0, 0);
}

static __device__ __forceinline__ float gatef(float a, float b){
  a = fminf(fmaxf(a, -20.f), 20.f);
  float e2a = __expf(2.f*a);
  float th = __fdividef(e2a - 1.f, e2a + 1.f);
  float sg = __fdividef(1.f, 1.f + __expf(-b));
  return th * sg;
}

union PK4 { uint64_t u; _Float16 h[4]; };

// ---------------- prep: convert/pack all weights to f16 MFMA-A layouts ----------------
__global__ void prep_kernel(const float* __restrict__ dil_w, const float* __restrict__ cond_w,
                            const float* __restrict__ res_w, const float* __restrict__ skip_w,
                            const float* __restrict__ cow, const float* __restrict__ cew,
                            const float* __restrict__ skip_b,
                            _Float16* __restrict__ WdT, _Float16* __restrict__ Wc,
                            _Float16* __restrict__ Wr, _Float16* __restrict__ Wsa,
                            _Float16* __restrict__ Wco, _Float16* __restrict__ Wce,
                            float* __restrict__ bsum)
{
  int g = blockIdx.x*256 + threadIdx.x;
  if (g < 262144){
    int r = g & 63, m = (g>>6) & 127, tap = (g>>13) & 1, l = g>>14;
    WdT[g] = (_Float16)dil_w[(((l*128+m)*64 + r)*2) + tap];
  } else if ((g -= 262144) < 196608){
    int o = g % 96; int rest = g / 96; int m = rest & 127; int l = rest >> 7;
    Wc[g] = (_Float16)((o < 80) ? cond_w[(l*128+m)*80 + o] : 0.f);
  } else if ((g -= 196608) < 61440){
    Wr[g] = (_Float16)res_w[g];
  } else if ((g -= 61440) < 262144){
    int kk = g & 1023, m = g >> 10; int l = kk >> 6, j = kk & 63;
    Wsa[g] = (_Float16)skip_w[(l*256+m)*64 + j];
  } else if ((g -= 262144) < 65536){
    Wco[g] = (_Float16)cow[g];
  } else if ((g -= 65536) < 65536){
    Wce[g] = (_Float16)cew[g];
  } else if ((g -= 65536) < 256){
    float s = 0.f;
    for (int l = 0; l < 16; l++) s += skip_b[l*256 + g];
    bsum[g] = s;
  }
}

// ---------------- wup_pack: up_w fp32 [o][i][1024] -> f16 Wup[(o*256+u)][ds*80+i] ------
// block (o, q): transposes a 64u x 320k tile through LDS; both phases coalesced.
__global__ __launch_bounds__(256) void wup_pack(const float* __restrict__ up_w,
                                                _Float16* __restrict__ Wup)
{
  __shared__ uint16_t ls[64*324];
  int o = blockIdx.x, q = blockIdx.y, tid = threadIdx.x;
  int u0 = q*64;
  for (int e = tid; e < 20480; e += 256){
    int kk = e >> 6, ul = e & 63;          // kk = ds*80+i
    int i = kk % 80, ds = kk / 80;
    float v = up_w[(size_t)o*81920 + (size_t)i*1024 + 256*ds + u0 + ul];
    _Float16 h = (_Float16)v;
    ls[ul*324 + kk] = *(uint16_t*)&h;
  }
  __syncthreads();
  for (int e = tid; e < 20480; e += 256){
    int ul = e / 320, k = e % 320;
    Wup[((size_t)(o*256 + u0 + ul))*320 + k] = *(_Float16*)&ls[ul*324 + k];
  }
}

// ---------------- featpack: feat fp32 [n][80][32] -> f16 Bp[(n*32+c)][ds*80+i] --------
__global__ __launch_bounds__(256) void featpack(const float* __restrict__ feat,
                                                _Float16* __restrict__ Bp)
{
  int g = blockIdx.x*256 + threadIdx.x;
  if (g < 40960){
    int col = g / 320, k = g % 320;
    int n = col >> 5, c = col & 31;
    int ds = k / 80, i = k % 80;
    float v = (c - ds >= 0) ? feat[(size_t)n*2560 + (size_t)i*32 + (c - ds)] : 0.f;
    Bp[g] = (_Float16)v;
  }
}

// ---------------- upsample GEMM: condh[n][t][o] = f16( Wup @ Bp + up_b[o] ) -----------
// M=(o,u)=20480 rows, N=(n,c)=128 cols, K=320. 320 blocks x 4 waves;
// wave = one 16-row m-tile x 8 col-tiles. t = c*256+u (guard t<8000).
__global__ __launch_bounds__(256) void upsample_gemm(
    const _Float16* __restrict__ Wup, const _Float16* __restrict__ Bp,
    const float* __restrict__ up_b, _Float16* __restrict__ condh)
{
  int tid = threadIdx.x;
  int lane = tid & 63, w = tid >> 6;
  int l16 = lane & 15, lg = lane >> 4;
  int mt = blockIdx.x*4 + w;
  int m0 = mt*16;
  int o = m0 >> 8;
  float ub = up_b[o];
  f32x4 acc[8];
  #pragma unroll
  for (int ct = 0; ct < 8; ct++){ f32x4 a; a[0]=0;a[1]=0;a[2]=0;a[3]=0; acc[ct]=a; }
  #pragma unroll
  for (int ks = 0; ks < 10; ks++){
    half8 a = *(const half8*)(Wup + (size_t)(m0 + l16)*320 + ks*32 + lg*8);
    #pragma unroll
    for (int ct = 0; ct < 8; ct++){
      half8 b = *(const half8*)(Bp + (size_t)(ct*16 + l16)*320 + ks*32 + lg*8);
      acc[ct] = MFMA16(a, b, acc[ct]);
    }
  }
  #pragma unroll
  for (int ct = 0; ct < 8; ct++){
    int col = ct*16 + l16;
    int n = col >> 5, c = col & 31;
    #pragma unroll
    for (int r = 0; r < 4; r++){
      int m = m0 + lg*4 + r;
      int u = m & 255;
      int t = c*256 + u;
      if (t < TT){
        _Float16 h = (_Float16)(acc[ct][r] + ub);
        condh[((size_t)n*TT + t)*96 + o] = h;
      }
    }
  }
}

// ---------------- embedding -> xf f32 + xh f16; also zero condh pad o in [80,96) ------
__global__ __launch_bounds__(256) void embed_kernel(
    const int* __restrict__ fi, const float* __restrict__ embed,
    float* __restrict__ xf, _Float16* __restrict__ xh, _Float16* __restrict__ condh)
{
  int tile = blockIdx.x, n = blockIdx.y;
  int tl = threadIdx.x >> 2, g = threadIdx.x & 3;
  int t0 = tile*64;
  int t = t0 + tl;
  int idx = fi[(size_t)n*TT + t];
  const float* er = embed + (size_t)idx*64 + g*16;
  float* xo = xf + ((size_t)n*TT + t)*64 + g*16;
  _Float16* ho = xh + ((size_t)n*TT + t)*64 + g*16;
  #pragma unroll
  for (int r = 0; r < 16; r++){
    float v = er[r];
    xo[r] = v;
    ho[r] = (_Float16)v;
  }
  uint32_t* cz = (uint32_t*)condh;
  for (int e = threadIdx.x; e < 512; e += 256){
    int ztl = e >> 3, j = e & 7;
    cz[((size_t)n*TT + t0 + ztl)*48 + 40 + j] = 0u;
  }
}

// ---------------- one residual layer, f16 MFMA, t-major activations -------------------
template<bool LAST>
__global__ __launch_bounds__(256) void layer_mfma(
    float* __restrict__ xf,               // [n][t][64] f32, in-place residual
    const _Float16* __restrict__ xh_in,   // [n][t][64] f16
    _Float16* __restrict__ xh_out,        // [n][t][64] f16
    const _Float16* __restrict__ condh,   // [n][t][96]
    _Float16* __restrict__ actsL,         // actsG + l*64, [n][t][1024]
    const _Float16* __restrict__ WdT,     // [2][128][64]
    const _Float16* __restrict__ Wc,      // [128][96]
    const _Float16* __restrict__ Wr,      // [64][64]
    const float* __restrict__ dil_b_l,
    const float* __restrict__ cond_b_l,
    const float* __restrict__ res_b_l,
    int d)
{
  __shared__ __attribute__((aligned(16))) char als[8192];  // [64 t][64 ch] f16, swizzled
  int bx = blockIdx.x;
  int tile = bx % 125, n = bx / 125;
  int tid = threadIdx.x;
  int lane = tid & 63;
  int w = tid >> 6;
  int t0 = tile*64;
  int l16 = lane & 15;
  int lg  = lane >> 4;
  const _Float16* xhn = xh_in + (size_t)n*TT*64;

  half8 aD[2][2][2];   // [tap][mi][ks]
  half8 aC[2][3];      // [mi][kc]
  #pragma unroll
  for (int mi = 0; mi < 2; mi++){
    int m = (w + 4*mi)*16 + l16;
    #pragma unroll
    for (int tap = 0; tap < 2; tap++)
      #pragma unroll
      for (int ks = 0; ks < 2; ks++)
        aD[tap][mi][ks] = *(const half8*)(WdT + ((size_t)(tap*128 + m)*64 + ks*32 + lg*8));
    #pragma unroll
    for (int kc = 0; kc < 3; kc++)
      aC[mi][kc] = *(const half8*)(Wc + ((size_t)m*96 + kc*32 + lg*8));
  }
  float bias[2][4];
  #pragma unroll
  for (int mi = 0; mi < 2; mi++)
    #pragma unroll
    for (int r = 0; r < 4; r++){
      int mm = (w + 4*mi)*16 + lg*4 + r;
      bias[mi][r] = dil_b_l[mm] + cond_b_l[mm];
    }

  f32x4 acc[2][4];
  #pragma unroll
  for (int nt = 0; nt < 4; nt++){
    int t = t0 + nt*16 + l16;
    int td = t - d;
    half8 bcur[2], bdel[2], bcnd[3];
    #pragma unroll
    for (int ks = 0; ks < 2; ks++)
      bcur[ks] = *(const half8*)(xhn + (size_t)t*64 + ks*32 + lg*8);
    if (td >= 0){
      #pragma unroll
      for (int ks = 0; ks < 2; ks++)
        bdel[ks] = *(const half8*)(xhn + (size_t)td*64 + ks*32 + lg*8);
    } else {
      #pragma unroll
      for (int ks = 0; ks < 2; ks++)
        #pragma unroll
        for (int j = 0; j < 8; j++) bdel[ks][j] = (_Float16)0.f;
    }
    #pragma unroll
    for (int kc = 0; kc < 3; kc++)
      bcnd[kc] = *(const half8*)(condh + ((size_t)n*TT + t)*96 + kc*32 + lg*8);

    #pragma unroll
    for (int mi = 0; mi < 2; mi++){
      f32x4 a; a[0]=bias[mi][0]; a[1]=bias[mi][1]; a[2]=bias[mi][2]; a[3]=bias[mi][3];
      a = MFMA16(aD[0][mi][0], bdel[0], a);
      a = MFMA16(aD[0][mi][1], bdel[1], a);
      a = MFMA16(aD[1][mi][0], bcur[0], a);
      a = MFMA16(aD[1][mi][1], bcur[1], a);
      a = MFMA16(aC[mi][0], bcnd[0], a);
      a = MFMA16(aC[mi][1], bcnd[1], a);
      a = MFMA16(aC[mi][2], bcnd[2], a);
      acc[mi][nt] = a;
    }
  }

  int ch0 = w*16 + lg*4;
  #pragma unroll
  for (int nt = 0; nt < 4; nt++){
    int tl = nt*16 + l16;
    PK4 pk;
    #pragma unroll
    for (int r = 0; r < 4; r++)
      pk.h[r] = (_Float16)gatef(acc[0][nt][r], acc[1][nt][r]);
    if (!LAST)
      *(uint64_t*)(als + tl*128 + ((ch0*2) ^ ((tl & 7) << 4))) = pk.u;
    *(uint64_t*)(actsL + ((size_t)n*TT + t0 + tl)*1024 + ch0) = pk.u;
  }

  if (!LAST){
    __syncthreads();
    half8 aR[2];
    int mr = w*16 + l16;
    #pragma unroll
    for (int ks = 0; ks < 2; ks++)
      aR[ks] = *(const half8*)(Wr + (size_t)mr*64 + ks*32 + lg*8);
    float rb[4];
    #pragma unroll
    for (int r = 0; r < 4; r++) rb[r] = res_b_l[w*16 + lg*4 + r];
    #pragma unroll
    for (int nt = 0; nt < 4; nt++){
      int tl = nt*16 + l16; int t = t0 + tl;
      half8 bA[2];
      #pragma unroll
      for (int ks = 0; ks < 2; ks++)
        bA[ks] = *(const half8*)(als + tl*128 + (((ks*32 + lg*8)*2) ^ ((tl & 7) << 4)));
      f32x4 rc; rc[0]=rb[0]; rc[1]=rb[1]; rc[2]=rb[2]; rc[3]=rb[3];
      rc = MFMA16(aR[0], bA[0], rc);
      rc = MFMA16(aR[1], bA[1], rc);
      float* xp = xf + ((size_t)n*TT + t)*64 + w*16 + lg*4;
      f32x4 xv = *(const f32x4*)xp;
      xv += rc;
      *(f32x4*)xp = xv;
      PK4 pk;
      #pragma unroll
      for (int r = 0; r < 4; r++) pk.h[r] = (_Float16)xv[r];
      *(uint64_t*)(xh_out + ((size_t)n*TT + t)*64 + w*16 + lg*4) = pk.u;
    }
  }
}

// ---------------- fused final: skip-sum(K=1024)->relu->conv_out->relu->conv_end->shift
__global__ __launch_bounds__(512) void final_fused(
    const _Float16* __restrict__ actsG,  // [n][t][1024]
    const _Float16* __restrict__ Wsa,    // [256][1024]
    const _Float16* __restrict__ Wco,    // [256][256]
    const _Float16* __restrict__ Wce,    // [256][256]
    const float* __restrict__ bsum,      // [256]
    float* __restrict__ out)             // [n][256][8000]
{
  __shared__ __attribute__((aligned(16))) char ls[32768]; // [64 t][256 ch] f16, swizzled
  int bx = blockIdx.x;
  int tile = bx % 125, n = bx / 125;
  int tid = threadIdx.x;
  int lane = tid & 63;
  int w = tid >> 6;         // 0..7
  int t0 = tile*64;
  int l16 = lane & 15;
  int lg  = lane >> 4;

  f32x4 acc[2][4];
  #pragma unroll
  for (int mi = 0; mi < 2; mi++)
    #pragma unroll
    for (int nt = 0; nt < 4; nt++){
      f32x4 a;
      #pragma unroll
      for (int r = 0; r < 4; r++) a[r] = bsum[(2*w+mi)*16 + lg*4 + r];
      acc[mi][nt] = a;
    }
  for (int ks = 0; ks < 32; ks++){
    half8 bf[4];
    #pragma unroll
    for (int nt = 0; nt < 4; nt++){
      int t = t0 + nt*16 + l16;
      bf[nt] = *(const half8*)(actsG + ((size_t)n*TT + t)*1024 + ks*32 + lg*8);
    }
    #pragma unroll
    for (int mi = 0; mi < 2; mi++){
      int m = (2*w+mi)*16 + l16;
      half8 af = *(const half8*)(Wsa + (size_t)m*1024 + ks*32 + lg*8);
      #pragma unroll
      for (int nt = 0; nt < 4; nt++) acc[mi][nt] = MFMA16(af, bf[nt], acc[mi][nt]);
    }
  }
  #pragma unroll
  for (int mi = 0; mi < 2; mi++){
    int c0 = (2*w+mi)*16 + lg*4;
    #pragma unroll
    for (int nt = 0; nt < 4; nt++){
      int tl = nt*16 + l16;
      PK4 pk;
      #pragma unroll
      for (int r = 0; r < 4; r++) pk.h[r] = (_Float16)fmaxf(acc[mi][nt][r], 0.f);
      *(uint64_t*)(ls + tl*512 + ((c0*2) ^ ((tl & 15) << 4))) = pk.u;
    }
  }
  __syncthreads();

  #pragma unroll
  for (int mi = 0; mi < 2; mi++)
    #pragma unroll
    for (int nt = 0; nt < 4; nt++){ f32x4 a; a[0]=0;a[1]=0;a[2]=0;a[3]=0; acc[mi][nt]=a; }
  #pragma unroll
  for (int ks = 0; ks < 8; ks++){
    half8 bf[4];
    #pragma unroll
    for (int nt = 0; nt < 4; nt++){
      int tl = nt*16 + l16;
      bf[nt] = *(const half8*)(ls + tl*512 + (((ks*32 + lg*8)*2) ^ ((tl & 15) << 4)));
    }
    #pragma unroll
    for (int mi = 0; mi < 2; mi++){
      int m = (2*w+mi)*16 + l16;
      half8 af = *(const half8*)(Wco + (size_t)m*256 + ks*32 + lg*8);
      #pragma unroll
      for (int nt = 0; nt < 4; nt++) acc[mi][nt] = MFMA16(af, bf[nt], acc[mi][nt]);
    }
  }
  __syncthreads();
  #pragma unroll
  for (int mi = 0; mi < 2; mi++){
    int c0 = (2*w+mi)*16 + lg*4;
    #pragma unroll
    for (int nt = 0; nt < 4; nt++){
      int tl = nt*16 + l16;
      PK4 pk;
      #pragma unroll
      for (int r = 0; r < 4; r++) pk.h[r] = (_Float16)fmaxf(acc[mi][nt][r], 0.f);
      *(uint64_t*)(ls + tl*512 + ((c0*2) ^ ((tl & 15) << 4))) = pk.u;
    }
  }
  __syncthreads();

  #pragma unroll
  for (int mi = 0; mi < 2; mi++)
    #pragma unroll
    for (int nt = 0; nt < 4; nt++){ f32x4 a; a[0]=0;a[1]=0;a[2]=0;a[3]=0; acc[mi][nt]=a; }
  #pragma unroll
  for (int ks = 0; ks < 8; ks++){
    half8 bf[4];
    #pragma unroll
    for (int nt = 0; nt < 4; nt++){
      int tl = nt*16 + l16;
      bf[nt] = *(const half8*)(ls + tl*512 + (((ks*32 + lg*8)*2) ^ ((tl & 15) << 4)));
    }
    #pragma unroll
    for (int mi = 0; mi < 2; mi++){
      int m = (2*w+mi)*16 + l16;
      half8 af = *(const half8*)(Wce + (size_t)m*256 + ks*32 + lg*8);
      #pragma unroll
      for (int nt = 0; nt < 4; nt++) acc[mi][nt] = MFMA16(af, bf[nt], acc[mi][nt]);
    }
  }
  #pragma unroll
  for (int mi = 0; mi < 2; mi++)
    #pragma unroll
    for (int nt = 0; nt < 4; nt++)
      #pragma unroll
      for (int r = 0; r < 4; r++){
        int m = (2*w+mi)*16 + lg*4 + r;
        int t = t0 + nt*16 + l16;
        size_t ob = ((size_t)n*256 + m)*TT;
        if (t + 1 < TT) out[ob + t + 1] = acc[mi][nt][r];
        if (t == 0)     out[ob] = 0.f;
      }
}

extern "C" void kernel_launch(void* const* d_in, const int* in_sizes, int n_in,
                              void* d_out, int out_size, void* d_ws, size_t ws_size,
                              hipStream_t stream)
{
  const float* feat   = (const float*)d_in[0];
  const int*   fi     = (const int*)  d_in[1];
  const float* embed  = (const float*)d_in[2];
  const float* up_w   = (const float*)d_in[3];
  const float* up_b   = (const float*)d_in[4];
  const float* cond_w = (const float*)d_in[5];
  const float* cond_b = (const float*)d_in[6];
  const float* dil_w  = (const float*)d_in[7];
  const float* dil_b  = (const float*)d_in[8];
  const float* res_w  = (const float*)d_in[9];
  const float* res_b  = (const float*)d_in[10];
  const float* skip_w = (const float*)d_in[11];
  const float* skip_b = (const float*)d_in[12];
  const float* cow    = (const float*)d_in[13];
  const float* cew    = (const float*)d_in[14];
  float* out = (float*)d_out;
  float* cur = (float*)d_ws;

  float*     xf    = cur;               cur += 2048000;   // [4][8000][64] f32
  _Float16*  xhA   = (_Float16*)cur;    cur += 1024000;   // [4][8000][64] f16
  _Float16*  xhB   = (_Float16*)cur;    cur += 1024000;
  _Float16*  condh = (_Float16*)cur;    cur += 1536000;   // [4][8000][96] f16 (3,072,000 halves)
  _Float16*  WdT   = (_Float16*)cur;    cur += 131072;
  _Float16*  Wc    = (_Float16*)cur;    cur += 98304;
  _Float16*  Wr    = (_Float16*)cur;    cur += 30720;
  _Float16*  Wsa   = (_Float16*)cur;    cur += 131072;
  _Float16*  Wco   = (_Float16*)cur;    cur += 32768;
  _Float16*  Wce   = (_Float16*)cur;    cur += 32768;
  float*     bsum  = cur;               cur += 256;
  _Float16*  actsG = (_Float16*)cur;                      // [4][8000][1024] f16 (32,768,000 halves)
  // Overlay: Wup (6,553,600 h) + Bp (40,960 h) live in actsG's tail; they are
  // consumed by upsample_gemm BEFORE any layer writes actsG (same-stream order).
  _Float16*  Wup   = actsG + (32768000 - 6553600);
  _Float16*  Bp    = Wup - 40960;

  prep_kernel<<<3569, 256, 0, stream>>>(dil_w, cond_w, res_w, skip_w, cow, cew, skip_b,
                                        WdT, Wc, Wr, Wsa, Wco, Wce, bsum);
  wup_pack<<<dim3(80,4), 256, 0, stream>>>(up_w, Wup);
  featpack<<<160, 256, 0, stream>>>(feat, Bp);
  embed_kernel<<<dim3(125,4), 256, 0, stream>>>(fi, embed, xf, xhA, condh);
  upsample_gemm<<<320, 256, 0, stream>>>(Wup, Bp, up_b, condh);

  const _Float16* xhin = xhA; _Float16* xhout = xhB;
  for (int l = 0; l < 16; l++){
    int dd = 1 << (l & 7);
    const _Float16* WdTl = WdT + (size_t)l*16384;
    const _Float16* Wcl  = Wc  + (size_t)l*12288;
    const _Float16* Wrl  = Wr  + (size_t)(l < 15 ? l : 0)*4096;
    const float*    rbl  = res_b + (size_t)(l < 15 ? l : 0)*64;
    _Float16* actsL = actsG + (size_t)l*64;
    if (l == 15)
      layer_mfma<true><<<500, 256, 0, stream>>>(xf, xhin, xhout, condh, actsL,
          WdTl, Wcl, Wrl, dil_b + l*128, cond_b + l*128, rbl, dd);
    else
      layer_mfma<false><<<500, 256, 0, stream>>>(xf, xhin, xhout, condh, actsL,
          WdTl, Wcl, Wrl, dil_b + l*128, cond_b + l*128, rbl, dd);
    const _Float16* nin = xhout; xhout = (_Float16*)xhin; xhin = nin;
  }

  final_fused<<<500, 512, 0, stream>>>(actsG, Wsa, Wco, Wce, bsum, out);
}